// Round 7
// baseline (61.390 us; speedup 1.0000x reference)
//
#include <hip/hip_runtime.h>
#include <hip/hip_bf16.h>

constexpr int BB = 4;
constexpr int SS = 1024;
constexpr int HH = 16;
constexpr int DH = 64;
constexpr int DM = 1024;

using f32x16 = __attribute__((ext_vector_type(16))) float;
using s16x8  = __attribute__((ext_vector_type(8))) short;

__device__ __forceinline__ f32x16 mfma32(s16x8 a, s16x8 b, f32x16 c) {
    return __builtin_amdgcn_mfma_f32_32x32x16_bf16(a, b, c, 0, 0, 0);
}

__device__ __forceinline__ unsigned short bf16bits(float x) {
    union { __hip_bfloat16 h; unsigned short s; } cv;
    cv.h = __float2bfloat16(x);
    return cv.s;
}
__device__ __forceinline__ unsigned pk_bf16(float lo, float hi) {
    return (unsigned)bf16bits(lo) | ((unsigned)bf16bits(hi) << 16);
}

__device__ __forceinline__ float fast_exp2(float x) {
#if __has_builtin(__builtin_amdgcn_exp2f)
    return __builtin_amdgcn_exp2f(x);
#else
    return __expf(x * 0.6931471805599453f);
#endif
}

// ---------------- QKV projection (MFMA) ---------------- (UNCHANGED from round 6)
__global__ __launch_bounds__(256) void qkv_proj_kernel(
    const float* __restrict__ x,
    const float* __restrict__ Wq, const float* __restrict__ Wk, const float* __restrict__ Wv,
    const float* __restrict__ bq, const float* __restrict__ bk, const float* __restrict__ bv,
    __hip_bfloat16* __restrict__ q_ws, __hip_bfloat16* __restrict__ k_ws,
    __hip_bfloat16* __restrict__ v_ws)
{
    const int bid  = blockIdx.x;
    const int tile = bid & 7;
    const int pair = bid >> 3;
    const int b = pair >> 4, h = pair & 15;
    const int t = threadIdx.x;
    const int w = t >> 6, l = t & 63;
    const int lq = l & 31, hi = l >> 5;
    const int s0 = tile * 128;

    __shared__ __align__(16) char Xs[16384];   // X stage [128 s][128B], then Q out
    __shared__ __align__(16) char Kt[16384];   // K out  [128 s][128B]
    __shared__ __align__(16) char Vt[16384];   // V out transposed [64 e][256B]

    {
        const float* xb = x + (size_t)(b * SS + s0) * DM + h * DH;
        #pragma unroll
        for (int i = 0; i < 8; ++i) {
            const int c  = t + 256 * i;
            const int r  = c >> 4, cw = c & 15;
            float4 v4 = *reinterpret_cast<const float4*>(xb + (size_t)r * DM + cw * 4);
            uint2 p;
            p.x = pk_bf16(v4.x, v4.y);
            p.y = pk_bf16(v4.z, v4.w);
            *reinterpret_cast<uint2*>(Xs + r * 128 + ((cw * 8) ^ ((r & 7) << 4))) = p;
        }
    }
    __syncthreads();

    const int arow = w * 32 + lq;
    const int asw  = (arow & 7) << 4;
    s16x8 af[4];
    #pragma unroll
    for (int s = 0; s < 4; ++s)
        af[s] = *reinterpret_cast<const s16x8*>(Xs + arow * 128 + ((s * 32 + hi * 16) ^ asw));
    __syncthreads();   // Xs now free for reuse as Q-out tile

    #pragma unroll
    for (int m = 0; m < 3; ++m) {
        const float* Wm = (m == 0) ? Wq : (m == 1) ? Wk : Wv;
        const float* bm = (m == 0) ? bq : (m == 1) ? bk : bv;

        f32x16 a0, a1;
        #pragma unroll
        for (int r = 0; r < 16; ++r) { a0[r] = 0.0f; a1[r] = 0.0f; }

        #pragma unroll
        for (int s = 0; s < 4; ++s) {
            const float* wp0 = Wm + (size_t)(h * DH + lq) * DH + s * 16 + hi * 8;
            const float* wp1 = wp0 + 32 * DH;
            float4 wa0 = reinterpret_cast<const float4*>(wp0)[0];
            float4 wb0 = reinterpret_cast<const float4*>(wp0)[1];
            float4 wa1 = reinterpret_cast<const float4*>(wp1)[0];
            float4 wb1 = reinterpret_cast<const float4*>(wp1)[1];
            union { unsigned u[4]; s16x8 v; } bf0, bf1;
            bf0.u[0] = pk_bf16(wa0.x, wa0.y); bf0.u[1] = pk_bf16(wa0.z, wa0.w);
            bf0.u[2] = pk_bf16(wb0.x, wb0.y); bf0.u[3] = pk_bf16(wb0.z, wb0.w);
            bf1.u[0] = pk_bf16(wa1.x, wa1.y); bf1.u[1] = pk_bf16(wa1.z, wa1.w);
            bf1.u[2] = pk_bf16(wb1.x, wb1.y); bf1.u[3] = pk_bf16(wb1.z, wb1.w);
            a0 = mfma32(af[s], bf0.v, a0);
            a1 = mfma32(af[s], bf1.v, a1);
        }

        const float bias0 = bm[h * DH + lq];
        const float bias1 = bm[h * DH + 32 + lq];

        if (m < 2) {
            char* T = (m == 0) ? Xs : Kt;
            #pragma unroll
            for (int r = 0; r < 16; ++r) {
                const int row = w * 32 + (r & 3) + 8 * (r >> 2) + 4 * hi;
                const int sw  = (row & 7) << 4;
                *reinterpret_cast<unsigned short*>(T + row * 128 + ((lq * 2) ^ sw)) =
                    bf16bits(a0[r] + bias0);
                *reinterpret_cast<unsigned short*>(T + row * 128 + (((32 + lq) * 2) ^ sw)) =
                    bf16bits(a1[r] + bias1);
            }
        } else {
            #pragma unroll
            for (int g = 0; g < 4; ++g) {
                const int off = w * 64 + g * 16 + hi * 8;
                uint2 p0, p1;
                p0.x = pk_bf16(a0[4*g+0] + bias0, a0[4*g+1] + bias0);
                p0.y = pk_bf16(a0[4*g+2] + bias0, a0[4*g+3] + bias0);
                p1.x = pk_bf16(a1[4*g+0] + bias1, a1[4*g+1] + bias1);
                p1.y = pk_bf16(a1[4*g+2] + bias1, a1[4*g+3] + bias1);
                *reinterpret_cast<uint2*>(Vt + lq * 256 + (off ^ ((lq & 7) << 4))) = p0;
                *reinterpret_cast<uint2*>(Vt + (32 + lq) * 256 + (off ^ (((32 + lq) & 7) << 4))) = p1;
            }
        }
    }
    __syncthreads();

    #pragma unroll
    for (int i = 0; i < 4; ++i) {
        const int c   = t + 256 * i;
        const int row = c >> 3, cc = c & 7;
        const int off = row * 128 + ((cc * 16) ^ ((row & 7) << 4));
        s16x8 qv = *reinterpret_cast<const s16x8*>(Xs + off);
        *reinterpret_cast<s16x8*>(q_ws + ((size_t)pair * SS + s0 + row) * DH + cc * 8) = qv;
        s16x8 kv = *reinterpret_cast<const s16x8*>(Kt + off);
        *reinterpret_cast<s16x8*>(k_ws + ((size_t)pair * SS + s0 + row) * DH + cc * 8) = kv;
    }
    #pragma unroll
    for (int i = 0; i < 4; ++i) {
        const int c   = t + 256 * i;
        const int row = c >> 4, cc = c & 15;
        s16x8 vv = *reinterpret_cast<const s16x8*>(
            Vt + row * 256 + ((cc * 16) ^ ((row & 7) << 4)));
        *reinterpret_cast<s16x8*>(v_ws + ((size_t)pair * DH + row) * SS + s0 + cc * 8) = vv;
    }
}

// ---------------- Flash attention: 8 waves = 4 q-groups x 2 KV-parities ----------------
// grid 512 = 64 pairs x 8 q-tiles (128 rows); block 512 = 8 waves.
// Wave (qg = w&3, p = w>>2): q-rows qg*32..+32, keys p*64..+64 of each 128-key super-tile.
// 8 super-tiles, double-buffered, ONE barrier each. End: split-K softmax merge via LDS.
// Occupancy: launch_bounds(512,4) -> <=128 VGPR -> 2 blocks/CU = 16 waves/CU (was 8).
__global__ __launch_bounds__(512, 4) void attn_kernel(
    const __hip_bfloat16* __restrict__ q_ws,
    const __hip_bfloat16* __restrict__ k_ws,
    const __hip_bfloat16* __restrict__ v_ws,
    float* __restrict__ out)
{
    const int bid  = blockIdx.x;
    const int lbid = (bid & 7) * 64 + (bid >> 3);   // XCD-aware swizzle (512 % 8 == 0)
    const int qt   = lbid & 7;
    const int pair = lbid >> 3;
    const int b = pair >> 4, h = pair & 15;
    const int t = threadIdx.x;
    const int w = t >> 6, l = t & 63;
    const int lq = l & 31, hi = l >> 5;
    const int qg = w & 3, p = w >> 2;

    // buf i at smem + i*32768: K [128 keys][128B] swz (row&7)<<4 ; V [64 d][256B] swz (row&15)<<4
    __shared__ __align__(16) char smem[65536];

    // Q fragments (B-operand): lane holds Q[q = qg*32+lq][16*s5 + 8*hi + 0..7]
    const __hip_bfloat16* qp =
        q_ws + ((size_t)pair * SS + qt * 128 + qg * 32 + lq) * DH + hi * 8;
    s16x8 qf[4];
    #pragma unroll
    for (int s5 = 0; s5 < 4; ++s5)
        qf[s5] = *reinterpret_cast<const s16x8*>(qp + s5 * 16);

    // staging: 512 threads x (2 K + 2 V) 16B chunks per 128-key super-tile
    const int u0 = t, u1 = t + 512;
    const __hip_bfloat16* kb = k_ws + (size_t)pair * SS * DH;
    const __hip_bfloat16* vb = v_ws + (size_t)pair * DH * SS;
    const int kOff0 = (u0 ^ ((u0 >> 3) & 7)) * 16;
    const int kOff1 = (u1 ^ ((u1 >> 3) & 7)) * 16;
    const int vOff0 = (u0 >> 4) * 256 + (((u0 & 15) ^ ((u0 >> 4) & 15)) << 4);
    const int vOff1 = (u1 >> 4) * 256 + (((u1 & 15) ^ ((u1 >> 4) & 15)) << 4);
    const size_t vs0 = (size_t)(u0 >> 4) * SS + (u0 & 15) * 8;
    const size_t vs1 = (size_t)(u1 >> 4) * SS + (u1 & 15) * 8;

    // prologue: super-tile 0 -> buf 0
    {
        s16x8 k0 = *reinterpret_cast<const s16x8*>(kb + u0 * 8);
        s16x8 k1 = *reinterpret_cast<const s16x8*>(kb + u1 * 8);
        s16x8 v0 = *reinterpret_cast<const s16x8*>(vb + vs0);
        s16x8 v1 = *reinterpret_cast<const s16x8*>(vb + vs1);
        *reinterpret_cast<s16x8*>(smem + kOff0) = k0;
        *reinterpret_cast<s16x8*>(smem + kOff1) = k1;
        *reinterpret_cast<s16x8*>(smem + 16384 + vOff0) = v0;
        *reinterpret_cast<s16x8*>(smem + 16384 + vOff1) = v1;
    }
    __syncthreads();

    f32x16 o0, o1;
    #pragma unroll
    for (int r = 0; r < 16; ++r) { o0[r] = 0.0f; o1[r] = 0.0f; }
    float m_run = -3.0e38f, lsum = 0.0f;
    const float cml = 0.18033688011112042f;  // log2(e)/8 : folds 1/sqrt(64) + exp2 domain

    const int kbase0 = (p * 64 + lq) * 128;
    const int kbase1 = kbase0 + 32 * 128;
    const int swzK = (lq & 7) << 4;
    const int swzV = (lq & 15) << 4;
    const int vrow0 = lq * 256, vrow1 = (32 + lq) * 256;

    int bufp = 0;
    s16x8 kr0, kr1, vr0, vr1;
    for (int st = 0; st < 8; ++st) {
        if (st < 7) {                              // T14: issue next super-tile loads first
            kr0 = *reinterpret_cast<const s16x8*>(kb + (st + 1) * 8192 + u0 * 8);
            kr1 = *reinterpret_cast<const s16x8*>(kb + (st + 1) * 8192 + u1 * 8);
            vr0 = *reinterpret_cast<const s16x8*>(vb + vs0 + (st + 1) * 128);
            vr1 = *reinterpret_cast<const s16x8*>(vb + vs1 + (st + 1) * 128);
        }
        const char* Kp = smem + bufp * 32768;
        const char* Vp = Kp + 16384;

        // QK^T (swapped): lane = query lq, regs = 32 keys (2 groups of 32 within parity half)
        f32x16 sc0, sc1;
        #pragma unroll
        for (int r = 0; r < 16; ++r) { sc0[r] = 0.0f; sc1[r] = 0.0f; }
        #pragma unroll
        for (int s5 = 0; s5 < 4; ++s5) {
            const int co = (2 * s5 + hi) << 4;
            s16x8 ka = *reinterpret_cast<const s16x8*>(Kp + kbase0 + (co ^ swzK));
            sc0 = mfma32(ka, qf[s5], sc0);
        }
        #pragma unroll
        for (int s5 = 0; s5 < 4; ++s5) {
            const int co = (2 * s5 + hi) << 4;
            s16x8 ka = *reinterpret_cast<const s16x8*>(Kp + kbase1 + (co ^ swzK));
            sc1 = mfma32(ka, qf[s5], sc1);
        }

        // online softmax: tree max, exp2 (folded scale), tree sum
        float tm[16];
        #pragma unroll
        for (int r = 0; r < 16; ++r) tm[r] = fmaxf(sc0[r], sc1[r]);
        #pragma unroll
        for (int s = 8; s >= 1; s >>= 1)
            #pragma unroll
            for (int r = 0; r < 8; ++r)
                if (r < s) tm[r] = fmaxf(tm[r], tm[r + s]);
        float mx = fmaxf(tm[0], __shfl_xor(tm[0], 32));

        if (!__all((mx - m_run) * cml <= 8.0f)) {  // T13 defer-rescale
            float mnew  = fmaxf(m_run, mx);
            float alpha = fast_exp2((m_run - mnew) * cml);
            lsum *= alpha;
            #pragma unroll
            for (int r = 0; r < 16; ++r) { o0[r] *= alpha; o1[r] *= alpha; }
            m_run = mnew;
        }
        const float nm = -m_run * cml;
        float ts[16];
        #pragma unroll
        for (int r = 0; r < 16; ++r) {
            sc0[r] = fast_exp2(fmaf(sc0[r], cml, nm));
            sc1[r] = fast_exp2(fmaf(sc1[r], cml, nm));
            ts[r]  = sc0[r] + sc1[r];
        }
        #pragma unroll
        for (int s = 8; s >= 1; s >>= 1)
            #pragma unroll
            for (int r = 0; r < 8; ++r)
                if (r < s) ts[r] += ts[r + s];
        lsum += ts[0] + __shfl_xor(ts[0], 32);

        // P -> A-frag via shfl_xor(32) half-exchange + PV
        #pragma unroll
        for (int s5 = 0; s5 < 4; ++s5) {
            const int sb8 = (s5 & 1) * 8;
            unsigned a0, b0, a1, b1;
            if (s5 < 2) {
                a0 = pk_bf16(sc0[sb8 + 0], sc0[sb8 + 1]);
                b0 = pk_bf16(sc0[sb8 + 4], sc0[sb8 + 5]);
                a1 = pk_bf16(sc0[sb8 + 2], sc0[sb8 + 3]);
                b1 = pk_bf16(sc0[sb8 + 6], sc0[sb8 + 7]);
            } else {
                a0 = pk_bf16(sc1[sb8 + 0], sc1[sb8 + 1]);
                b0 = pk_bf16(sc1[sb8 + 4], sc1[sb8 + 5]);
                a1 = pk_bf16(sc1[sb8 + 2], sc1[sb8 + 3]);
                b1 = pk_bf16(sc1[sb8 + 6], sc1[sb8 + 7]);
            }
            const unsigned sa0 = (unsigned)__shfl_xor((int)a0, 32);
            const unsigned sb0 = (unsigned)__shfl_xor((int)b0, 32);
            const unsigned sa1 = (unsigned)__shfl_xor((int)a1, 32);
            const unsigned sb1 = (unsigned)__shfl_xor((int)b1, 32);
            union { unsigned u[4]; s16x8 v; } afr;
            afr.u[0] = hi ? sb0 : a0;
            afr.u[1] = hi ? sb1 : a1;
            afr.u[2] = hi ? b0 : sa0;
            afr.u[3] = hi ? b1 : sa1;
            const int co = (2 * s5 + hi) << 4;
            s16x8 vb0 = *reinterpret_cast<const s16x8*>(Vp + vrow0 + ((p * 128 + co) ^ swzV));
            o0 = mfma32(afr.v, vb0, o0);
            s16x8 vb1 = *reinterpret_cast<const s16x8*>(Vp + vrow1 + ((p * 128 + co) ^ swzV));
            o1 = mfma32(afr.v, vb1, o1);
        }

        if (st < 7) {                              // write next super-tile into other buffer
            char* Kn = smem + (bufp ^ 1) * 32768;
            *reinterpret_cast<s16x8*>(Kn + kOff0) = kr0;
            *reinterpret_cast<s16x8*>(Kn + kOff1) = kr1;
            *reinterpret_cast<s16x8*>(Kn + 16384 + vOff0) = vr0;
            *reinterpret_cast<s16x8*>(Kn + 16384 + vOff1) = vr1;
        }
        __syncthreads();
        bufp ^= 1;
    }

    // split-K softmax merge between partner waves (qg, p=0) <- (qg, p=1), LDS reused
    float* Obuf = reinterpret_cast<float*>(smem + qg * 8192);          // [32 q][64 d] f32
    float* mlb  = reinterpret_cast<float*>(smem + 32768 + qg * 256);   // m[32], l[32]
    if (p == 1) {
        #pragma unroll
        for (int r = 0; r < 16; ++r) {
            const int qr = (r & 3) + 8 * (r >> 2) + 4 * hi;
            Obuf[qr * 64 + lq]      = o0[r];
            Obuf[qr * 64 + 32 + lq] = o1[r];
        }
        mlb[lq]      = m_run;
        mlb[32 + lq] = lsum;
    }
    __syncthreads();
    if (p == 0) {
        const float m1 = mlb[lq];
        const float l1 = mlb[32 + lq];
        const float M  = fmaxf(m_run, m1);
        const float e0 = fast_exp2((m_run - M) * cml);
        const float e1 = fast_exp2((m1 - M) * cml);
        const float inv = 1.0f / fmaf(lsum, e0, l1 * e1);
        const float f0 = e0 * inv, f1 = e1 * inv;
        #pragma unroll
        for (int r = 0; r < 16; ++r) {
            const int qr = (r & 3) + 8 * (r >> 2) + 4 * hi;
            const float f0r = __shfl(f0, qr);
            const float f1r = __shfl(f1, qr);
            float* op = out + ((size_t)b * SS + qt * 128 + qg * 32 + qr) * DM + h * DH + lq;
            op[0]  = o0[r] * f0r + Obuf[qr * 64 + lq]      * f1r;
            op[32] = o1[r] * f0r + Obuf[qr * 64 + 32 + lq] * f1r;
        }
    }
}

extern "C" void kernel_launch(void* const* d_in, const int* in_sizes, int n_in,
                              void* d_out, int out_size, void* d_ws, size_t ws_size,
                              hipStream_t stream) {
    const float* x  = (const float*)d_in[0];
    const float* Wq = (const float*)d_in[1];
    const float* Wk = (const float*)d_in[2];
    const float* Wv = (const float*)d_in[3];
    const float* bq = (const float*)d_in[4];
    const float* bk = (const float*)d_in[5];
    const float* bv = (const float*)d_in[6];
    float* out = (float*)d_out;

    __hip_bfloat16* q_ws = (__hip_bfloat16*)d_ws;
    __hip_bfloat16* k_ws = q_ws + (size_t)BB * HH * SS * DH;
    __hip_bfloat16* v_ws = k_ws + (size_t)BB * HH * SS * DH;

    qkv_proj_kernel<<<dim3(BB * HH * (SS / 128)), dim3(256), 0, stream>>>(
        x, Wq, Wk, Wv, bq, bk, bv, q_ws, k_ws, v_ws);
    attn_kernel<<<dim3(BB * HH * (SS / 128)), dim3(512), 0, stream>>>(
        q_ws, k_ws, v_ws, out);
}

// Round 8
// 56.450 us; speedup vs baseline: 1.0875x; 1.0875x over previous
//
#include <hip/hip_runtime.h>
#include <hip/hip_bf16.h>

constexpr int BB = 4;
constexpr int SS = 1024;
constexpr int HH = 16;
constexpr int DH = 64;
constexpr int DM = 1024;

using f32x16 = __attribute__((ext_vector_type(16))) float;
using s16x8  = __attribute__((ext_vector_type(8))) short;

__device__ __forceinline__ f32x16 mfma32(s16x8 a, s16x8 b, f32x16 c) {
    return __builtin_amdgcn_mfma_f32_32x32x16_bf16(a, b, c, 0, 0, 0);
}

__device__ __forceinline__ unsigned short bf16bits(float x) {
    union { __hip_bfloat16 h; unsigned short s; } cv;
    cv.h = __float2bfloat16(x);
    return cv.s;
}
__device__ __forceinline__ unsigned pk_bf16(float lo, float hi) {
    return (unsigned)bf16bits(lo) | ((unsigned)bf16bits(hi) << 16);
}

__device__ __forceinline__ float fast_exp2(float x) {
#if __has_builtin(__builtin_amdgcn_exp2f)
    return __builtin_amdgcn_exp2f(x);
#else
    return __expf(x * 0.6931471805599453f);
#endif
}

// ---------------- QKV projection (MFMA) ---------------- (UNCHANGED from round 6/7)
__global__ __launch_bounds__(256) void qkv_proj_kernel(
    const float* __restrict__ x,
    const float* __restrict__ Wq, const float* __restrict__ Wk, const float* __restrict__ Wv,
    const float* __restrict__ bq, const float* __restrict__ bk, const float* __restrict__ bv,
    __hip_bfloat16* __restrict__ q_ws, __hip_bfloat16* __restrict__ k_ws,
    __hip_bfloat16* __restrict__ v_ws)
{
    const int bid  = blockIdx.x;
    const int tile = bid & 7;
    const int pair = bid >> 3;
    const int b = pair >> 4, h = pair & 15;
    const int t = threadIdx.x;
    const int w = t >> 6, l = t & 63;
    const int lq = l & 31, hi = l >> 5;
    const int s0 = tile * 128;

    __shared__ __align__(16) char Xs[16384];   // X stage [128 s][128B], then Q out
    __shared__ __align__(16) char Kt[16384];   // K out  [128 s][128B]
    __shared__ __align__(16) char Vt[16384];   // V out transposed [64 e][256B]

    {
        const float* xb = x + (size_t)(b * SS + s0) * DM + h * DH;
        #pragma unroll
        for (int i = 0; i < 8; ++i) {
            const int c  = t + 256 * i;
            const int r  = c >> 4, cw = c & 15;
            float4 v4 = *reinterpret_cast<const float4*>(xb + (size_t)r * DM + cw * 4);
            uint2 p;
            p.x = pk_bf16(v4.x, v4.y);
            p.y = pk_bf16(v4.z, v4.w);
            *reinterpret_cast<uint2*>(Xs + r * 128 + ((cw * 8) ^ ((r & 7) << 4))) = p;
        }
    }
    __syncthreads();

    const int arow = w * 32 + lq;
    const int asw  = (arow & 7) << 4;
    s16x8 af[4];
    #pragma unroll
    for (int s = 0; s < 4; ++s)
        af[s] = *reinterpret_cast<const s16x8*>(Xs + arow * 128 + ((s * 32 + hi * 16) ^ asw));
    __syncthreads();   // Xs now free for reuse as Q-out tile

    #pragma unroll
    for (int m = 0; m < 3; ++m) {
        const float* Wm = (m == 0) ? Wq : (m == 1) ? Wk : Wv;
        const float* bm = (m == 0) ? bq : (m == 1) ? bk : bv;

        f32x16 a0, a1;
        #pragma unroll
        for (int r = 0; r < 16; ++r) { a0[r] = 0.0f; a1[r] = 0.0f; }

        #pragma unroll
        for (int s = 0; s < 4; ++s) {
            const float* wp0 = Wm + (size_t)(h * DH + lq) * DH + s * 16 + hi * 8;
            const float* wp1 = wp0 + 32 * DH;
            float4 wa0 = reinterpret_cast<const float4*>(wp0)[0];
            float4 wb0 = reinterpret_cast<const float4*>(wp0)[1];
            float4 wa1 = reinterpret_cast<const float4*>(wp1)[0];
            float4 wb1 = reinterpret_cast<const float4*>(wp1)[1];
            union { unsigned u[4]; s16x8 v; } bf0, bf1;
            bf0.u[0] = pk_bf16(wa0.x, wa0.y); bf0.u[1] = pk_bf16(wa0.z, wa0.w);
            bf0.u[2] = pk_bf16(wb0.x, wb0.y); bf0.u[3] = pk_bf16(wb0.z, wb0.w);
            bf1.u[0] = pk_bf16(wa1.x, wa1.y); bf1.u[1] = pk_bf16(wa1.z, wa1.w);
            bf1.u[2] = pk_bf16(wb1.x, wb1.y); bf1.u[3] = pk_bf16(wb1.z, wb1.w);
            a0 = mfma32(af[s], bf0.v, a0);
            a1 = mfma32(af[s], bf1.v, a1);
        }

        const float bias0 = bm[h * DH + lq];
        const float bias1 = bm[h * DH + 32 + lq];

        if (m < 2) {
            char* T = (m == 0) ? Xs : Kt;
            #pragma unroll
            for (int r = 0; r < 16; ++r) {
                const int row = w * 32 + (r & 3) + 8 * (r >> 2) + 4 * hi;
                const int sw  = (row & 7) << 4;
                *reinterpret_cast<unsigned short*>(T + row * 128 + ((lq * 2) ^ sw)) =
                    bf16bits(a0[r] + bias0);
                *reinterpret_cast<unsigned short*>(T + row * 128 + (((32 + lq) * 2) ^ sw)) =
                    bf16bits(a1[r] + bias1);
            }
        } else {
            #pragma unroll
            for (int g = 0; g < 4; ++g) {
                const int off = w * 64 + g * 16 + hi * 8;
                uint2 p0, p1;
                p0.x = pk_bf16(a0[4*g+0] + bias0, a0[4*g+1] + bias0);
                p0.y = pk_bf16(a0[4*g+2] + bias0, a0[4*g+3] + bias0);
                p1.x = pk_bf16(a1[4*g+0] + bias1, a1[4*g+1] + bias1);
                p1.y = pk_bf16(a1[4*g+2] + bias1, a1[4*g+3] + bias1);
                *reinterpret_cast<uint2*>(Vt + lq * 256 + (off ^ ((lq & 7) << 4))) = p0;
                *reinterpret_cast<uint2*>(Vt + (32 + lq) * 256 + (off ^ (((32 + lq) & 7) << 4))) = p1;
            }
        }
    }
    __syncthreads();

    #pragma unroll
    for (int i = 0; i < 4; ++i) {
        const int c   = t + 256 * i;
        const int row = c >> 3, cc = c & 7;
        const int off = row * 128 + ((cc * 16) ^ ((row & 7) << 4));
        s16x8 qv = *reinterpret_cast<const s16x8*>(Xs + off);
        *reinterpret_cast<s16x8*>(q_ws + ((size_t)pair * SS + s0 + row) * DH + cc * 8) = qv;
        s16x8 kv = *reinterpret_cast<const s16x8*>(Kt + off);
        *reinterpret_cast<s16x8*>(k_ws + ((size_t)pair * SS + s0 + row) * DH + cc * 8) = kv;
    }
    #pragma unroll
    for (int i = 0; i < 4; ++i) {
        const int c   = t + 256 * i;
        const int row = c >> 4, cc = c & 15;
        s16x8 vv = *reinterpret_cast<const s16x8*>(
            Vt + row * 256 + ((cc * 16) ^ ((row & 7) << 4)));
        *reinterpret_cast<s16x8*>(v_ws + ((size_t)pair * DH + row) * SS + s0 + cc * 8) = vv;
    }
}

// ---------------- Flash attention: 8 waves = 4 q-groups x 2 KV-parities ----------------
// grid 512; block 512 = 8 waves. NEW (round 8): K stored into LDS with key-permutation
// pi (swap rows 4-7<->8-11, 20-23<->24-27 within each 32-row group; pi(g)=g^12 when
// (g&12) in {4,8}). After swapped QK^T, lane (lq,hi)'s 16 score regs per 32-key group
// are EXACTLY the keys its PV A-fragments need (8hi+0..7 from regs 0-7, 16+8hi+0..7
// from regs 8-15) -> P->A repack is pure in-lane pk_bf16, ZERO cross-lane shfl.
__global__ __launch_bounds__(512, 4) void attn_kernel(
    const __hip_bfloat16* __restrict__ q_ws,
    const __hip_bfloat16* __restrict__ k_ws,
    const __hip_bfloat16* __restrict__ v_ws,
    float* __restrict__ out)
{
    const int bid  = blockIdx.x;
    const int lbid = (bid & 7) * 64 + (bid >> 3);   // XCD-aware swizzle (512 % 8 == 0)
    const int qt   = lbid & 7;
    const int pair = lbid >> 3;
    const int b = pair >> 4, h = pair & 15;
    const int t = threadIdx.x;
    const int w = t >> 6, l = t & 63;
    const int lq = l & 31, hi = l >> 5;
    const int qg = w & 3, p = w >> 2;

    // buf i at smem + i*32768: K [128 keys][128B] swz (row&7)<<4 ; V [64 d][256B] swz (row&15)<<4
    __shared__ __align__(16) char smem[65536];

    // Q fragments (B-operand): lane holds Q[q = qg*32+lq][16*s5 + 8*hi + 0..7]
    const __hip_bfloat16* qp =
        q_ws + ((size_t)pair * SS + qt * 128 + qg * 32 + lq) * DH + hi * 8;
    s16x8 qf[4];
    #pragma unroll
    for (int s5 = 0; s5 < 4; ++s5)
        qf[s5] = *reinterpret_cast<const s16x8*>(qp + s5 * 16);

    // staging: 512 threads x (2 K + 2 V) 16B chunks per 128-key super-tile.
    // K dest row is pi-permuted; swizzle uses the PERMUTED row (what the reader uses).
    const int u0 = t, u1 = t + 512;
    const __hip_bfloat16* kb = k_ws + (size_t)pair * SS * DH;
    const __hip_bfloat16* vb = v_ws + (size_t)pair * DH * SS;

    const int r0g = (u0 >> 3) & 31, r0m = r0g & 12;
    const int pr0 = (u0 >> 3 & ~31) | ((r0m == 4 || r0m == 8) ? (r0g ^ 12) : r0g);
    const int kOff0 = pr0 * 128 + (((u0 & 7) ^ (pr0 & 7)) << 4);
    const int r1g = (u1 >> 3) & 31, r1m = r1g & 12;
    const int pr1 = (u1 >> 3 & ~31) | ((r1m == 4 || r1m == 8) ? (r1g ^ 12) : r1g);
    const int kOff1 = pr1 * 128 + (((u1 & 7) ^ (pr1 & 7)) << 4);

    const int vOff0 = (u0 >> 4) * 256 + (((u0 & 15) ^ ((u0 >> 4) & 15)) << 4);
    const int vOff1 = (u1 >> 4) * 256 + (((u1 & 15) ^ ((u1 >> 4) & 15)) << 4);
    const size_t vs0 = (size_t)(u0 >> 4) * SS + (u0 & 15) * 8;
    const size_t vs1 = (size_t)(u1 >> 4) * SS + (u1 & 15) * 8;

    // prologue: super-tile 0 -> buf 0
    {
        s16x8 k0 = *reinterpret_cast<const s16x8*>(kb + u0 * 8);
        s16x8 k1 = *reinterpret_cast<const s16x8*>(kb + u1 * 8);
        s16x8 v0 = *reinterpret_cast<const s16x8*>(vb + vs0);
        s16x8 v1 = *reinterpret_cast<const s16x8*>(vb + vs1);
        *reinterpret_cast<s16x8*>(smem + kOff0) = k0;
        *reinterpret_cast<s16x8*>(smem + kOff1) = k1;
        *reinterpret_cast<s16x8*>(smem + 16384 + vOff0) = v0;
        *reinterpret_cast<s16x8*>(smem + 16384 + vOff1) = v1;
    }
    __syncthreads();

    f32x16 o0, o1;
    #pragma unroll
    for (int r = 0; r < 16; ++r) { o0[r] = 0.0f; o1[r] = 0.0f; }
    float m_run = -3.0e38f, lsum = 0.0f;
    const float cml = 0.18033688011112042f;  // log2(e)/8 : folds 1/sqrt(64) + exp2 domain

    const int kbase0 = (p * 64 + lq) * 128;
    const int kbase1 = kbase0 + 32 * 128;
    const int swzK = (lq & 7) << 4;
    const int swzV = (lq & 15) << 4;
    const int vrow0 = lq * 256, vrow1 = (32 + lq) * 256;

    int bufp = 0;
    s16x8 kr0, kr1, vr0, vr1;
    for (int st = 0; st < 8; ++st) {
        if (st < 7) {                              // T14: issue next super-tile loads first
            kr0 = *reinterpret_cast<const s16x8*>(kb + (st + 1) * 8192 + u0 * 8);
            kr1 = *reinterpret_cast<const s16x8*>(kb + (st + 1) * 8192 + u1 * 8);
            vr0 = *reinterpret_cast<const s16x8*>(vb + vs0 + (st + 1) * 128);
            vr1 = *reinterpret_cast<const s16x8*>(vb + vs1 + (st + 1) * 128);
        }
        const char* Kp = smem + bufp * 32768;
        const char* Vp = Kp + 16384;

        // QK^T (swapped): lane = query lq; regs = 32 pi-permuted keys of the parity half
        f32x16 sc0, sc1;
        #pragma unroll
        for (int r = 0; r < 16; ++r) { sc0[r] = 0.0f; sc1[r] = 0.0f; }
        #pragma unroll
        for (int s5 = 0; s5 < 4; ++s5) {
            const int co = (2 * s5 + hi) << 4;
            s16x8 ka = *reinterpret_cast<const s16x8*>(Kp + kbase0 + (co ^ swzK));
            sc0 = mfma32(ka, qf[s5], sc0);
        }
        #pragma unroll
        for (int s5 = 0; s5 < 4; ++s5) {
            const int co = (2 * s5 + hi) << 4;
            s16x8 ka = *reinterpret_cast<const s16x8*>(Kp + kbase1 + (co ^ swzK));
            sc1 = mfma32(ka, qf[s5], sc1);
        }

        // online softmax: tree max, exp2 (folded scale), tree sum (pi = relabeling only)
        float tm[16];
        #pragma unroll
        for (int r = 0; r < 16; ++r) tm[r] = fmaxf(sc0[r], sc1[r]);
        #pragma unroll
        for (int s = 8; s >= 1; s >>= 1)
            #pragma unroll
            for (int r = 0; r < 8; ++r)
                if (r < s) tm[r] = fmaxf(tm[r], tm[r + s]);
        float mx = fmaxf(tm[0], __shfl_xor(tm[0], 32));

        if (!__all((mx - m_run) * cml <= 8.0f)) {  // T13 defer-rescale
            float mnew  = fmaxf(m_run, mx);
            float alpha = fast_exp2((m_run - mnew) * cml);
            lsum *= alpha;
            #pragma unroll
            for (int r = 0; r < 16; ++r) { o0[r] *= alpha; o1[r] *= alpha; }
            m_run = mnew;
        }
        const float nm = -m_run * cml;
        float ts[16];
        #pragma unroll
        for (int r = 0; r < 16; ++r) {
            sc0[r] = fast_exp2(fmaf(sc0[r], cml, nm));
            sc1[r] = fast_exp2(fmaf(sc1[r], cml, nm));
            ts[r]  = sc0[r] + sc1[r];
        }
        #pragma unroll
        for (int s = 8; s >= 1; s >>= 1)
            #pragma unroll
            for (int r = 0; r < 8; ++r)
                if (r < s) ts[r] += ts[r + s];
        lsum += ts[0] + __shfl_xor(ts[0], 32);

        // P -> A-frag: PURE in-lane packing (pi made each lane self-sufficient) + PV
        #pragma unroll
        for (int s5 = 0; s5 < 4; ++s5) {
            const int base = (s5 & 1) * 8;
            union { unsigned u[4]; s16x8 v; } afr;
            if (s5 < 2) {
                afr.u[0] = pk_bf16(sc0[base + 0], sc0[base + 1]);
                afr.u[1] = pk_bf16(sc0[base + 2], sc0[base + 3]);
                afr.u[2] = pk_bf16(sc0[base + 4], sc0[base + 5]);
                afr.u[3] = pk_bf16(sc0[base + 6], sc0[base + 7]);
            } else {
                afr.u[0] = pk_bf16(sc1[base + 0], sc1[base + 1]);
                afr.u[1] = pk_bf16(sc1[base + 2], sc1[base + 3]);
                afr.u[2] = pk_bf16(sc1[base + 4], sc1[base + 5]);
                afr.u[3] = pk_bf16(sc1[base + 6], sc1[base + 7]);
            }
            const int co = (2 * s5 + hi) << 4;
            s16x8 vb0 = *reinterpret_cast<const s16x8*>(Vp + vrow0 + ((p * 128 + co) ^ swzV));
            o0 = mfma32(afr.v, vb0, o0);
            s16x8 vb1 = *reinterpret_cast<const s16x8*>(Vp + vrow1 + ((p * 128 + co) ^ swzV));
            o1 = mfma32(afr.v, vb1, o1);
        }

        if (st < 7) {                              // write next super-tile into other buffer
            char* Kn = smem + (bufp ^ 1) * 32768;
            *reinterpret_cast<s16x8*>(Kn + kOff0) = kr0;
            *reinterpret_cast<s16x8*>(Kn + kOff1) = kr1;
            *reinterpret_cast<s16x8*>(Kn + 16384 + vOff0) = vr0;
            *reinterpret_cast<s16x8*>(Kn + 16384 + vOff1) = vr1;
        }
        __syncthreads();
        bufp ^= 1;
    }

    // split-K softmax merge between partner waves (qg, p=0) <- (qg, p=1), LDS reused
    float* Obuf = reinterpret_cast<float*>(smem + qg * 8192);          // [32 q][64 d] f32
    float* mlb  = reinterpret_cast<float*>(smem + 32768 + qg * 256);   // m[32], l[32]
    if (p == 1) {
        #pragma unroll
        for (int r = 0; r < 16; ++r) {
            const int qr = (r & 3) + 8 * (r >> 2) + 4 * hi;
            Obuf[qr * 64 + lq]      = o0[r];
            Obuf[qr * 64 + 32 + lq] = o1[r];
        }
        mlb[lq]      = m_run;
        mlb[32 + lq] = lsum;
    }
    __syncthreads();
    if (p == 0) {
        const float m1 = mlb[lq];
        const float l1 = mlb[32 + lq];
        const float M  = fmaxf(m_run, m1);
        const float e0 = fast_exp2((m_run - M) * cml);
        const float e1 = fast_exp2((m1 - M) * cml);
        const float inv = 1.0f / fmaf(lsum, e0, l1 * e1);
        const float f0 = e0 * inv, f1 = e1 * inv;
        #pragma unroll
        for (int r = 0; r < 16; ++r) {
            const int qr = (r & 3) + 8 * (r >> 2) + 4 * hi;
            const float f0r = __shfl(f0, qr);
            const float f1r = __shfl(f1, qr);
            float* op = out + ((size_t)b * SS + qt * 128 + qg * 32 + qr) * DM + h * DH + lq;
            op[0]  = o0[r] * f0r + Obuf[qr * 64 + lq]      * f1r;
            op[32] = o1[r] * f0r + Obuf[qr * 64 + 32 + lq] * f1r;
        }
    }
}

extern "C" void kernel_launch(void* const* d_in, const int* in_sizes, int n_in,
                              void* d_out, int out_size, void* d_ws, size_t ws_size,
                              hipStream_t stream) {
    const float* x  = (const float*)d_in[0];
    const float* Wq = (const float*)d_in[1];
    const float* Wk = (const float*)d_in[2];
    const float* Wv = (const float*)d_in[3];
    const float* bq = (const float*)d_in[4];
    const float* bk = (const float*)d_in[5];
    const float* bv = (const float*)d_in[6];
    float* out = (float*)d_out;

    __hip_bfloat16* q_ws = (__hip_bfloat16*)d_ws;
    __hip_bfloat16* k_ws = q_ws + (size_t)BB * HH * SS * DH;
    __hip_bfloat16* v_ws = k_ws + (size_t)BB * HH * SS * DH;

    qkv_proj_kernel<<<dim3(BB * HH * (SS / 128)), dim3(256), 0, stream>>>(
        x, Wq, Wk, Wv, bq, bk, bv, q_ws, k_ws, v_ws);
    attn_kernel<<<dim3(BB * HH * (SS / 128)), dim3(512), 0, stream>>>(
        q_ws, k_ws, v_ws, out);
}